// Round 2
// baseline (951.779 us; speedup 1.0000x reference)
//
#include <hip/hip_runtime.h>

typedef _Float16 half8 __attribute__((ext_vector_type(8)));
typedef float    floatx4 __attribute__((ext_vector_type(4)));
typedef unsigned short u16;

constexpr int Bn  = 8;
constexpr int Sq  = 2048;   // S1 == S2
constexpr int KD  = 512;    // K1_DIM == K2_DIM
constexpr int PKD = 256;
constexpr int AD  = 512;    // ATT_DIM
constexpr int DV  = 512;

// ---------------------------------------------------------------------------
// transpose + cast f32 -> f16:  out[j][i] = (f16) in[i][j]
// in: [inRows][inCols] f32, out: [inCols][inRows] f16, batched via blockIdx.z
// ---------------------------------------------------------------------------
__global__ __launch_bounds__(256)
void transpose_cast_k(const float* __restrict__ in, _Float16* __restrict__ out,
                      int inRows, int inCols, long long bsIn, long long bsOut)
{
    __shared__ float t[32][33];
    const int b = blockIdx.z;
    in  += (long long)b * bsIn;
    out += (long long)b * bsOut;
    const int tx = threadIdx.x & 31;
    const int ty = threadIdx.x >> 5;     // 0..7
    const int c0 = blockIdx.x * 32;
    const int r0 = blockIdx.y * 32;
#pragma unroll
    for (int i = 0; i < 4; ++i)
        t[ty + 8*i][tx] = in[(long long)(r0 + ty + 8*i) * inCols + c0 + tx];
    __syncthreads();
#pragma unroll
    for (int i = 0; i < 4; ++i)
        out[(long long)(c0 + ty + 8*i) * inRows + r0 + tx] = (_Float16)t[tx][ty + 8*i];
}

// ---------------------------------------------------------------------------
// 128x128x32 fp16 MFMA GEMM.  C[M][N] = A[M][K] * B^T  (B stored [N][K], f16)
// A either f32 (converted on stage; optional two-segment concat via Ksplit)
// or f16.  Output f32, or f16 (+f32 bias) for the projection phase.
// 256 threads = 4 waves in 2x2, each wave 64x64 = 4x4 of 16x16x32 MFMA.
// ---------------------------------------------------------------------------
template<bool A_F32, bool OUT_F16>
__global__ __launch_bounds__(256, 2)
void gemm_k(const void* __restrict__ A1v, const void* __restrict__ A2v, int Ksplit,
            int lda1, int lda2, long long bsA,
            const _Float16* __restrict__ Bm, int ldb, long long bsB,
            void* __restrict__ Cv, int ldc, long long bsC,
            const float* __restrict__ bias, int K)
{
    // +8 f16 pad (16B) -> row stride 80B = 20 banks: conflict-free b128 reads
    __shared__ __align__(16) _Float16 As[128][40];
    __shared__ __align__(16) _Float16 Bs[128][40];

    const int tid  = threadIdx.x;
    const int lane = tid & 63;
    const int wave = tid >> 6;
    const int wm   = (wave >> 1) * 64;
    const int wn   = (wave & 1) * 64;
    const int fr   = lane & 15;       // frag row (A) / col (B,D)
    const int fq   = lane >> 4;       // quad: k-offset fq*8, D-row fq*4

    const int tm = blockIdx.y, tn = blockIdx.x, bz = blockIdx.z;

    const int srow = tid >> 1;          // staging row 0..127
    const int sseg = (tid & 1) * 16;    // 0 or 16 within the 32-wide k tile

    const long long aRow = (long long)(tm * 128 + srow);
    const u16* Bsrc = (const u16*)(Bm + (long long)bz * bsB)
                    + (long long)(tn * 128 + srow) * ldb + sseg;

    floatx4 acc[4][4];
#pragma unroll
    for (int i = 0; i < 4; ++i)
#pragma unroll
        for (int j = 0; j < 4; ++j) acc[i][j] = (floatx4)0.0f;

    for (int k0 = 0; k0 < K; k0 += 32) {
        uint4 a0, a1;
        if (A_F32) {
            const int kk = k0 + sseg;
            const float* Ap;
            if (kk < Ksplit)
                Ap = (const float*)A1v + (long long)bz * bsA + aRow * lda1 + kk;
            else
                Ap = (const float*)A2v + aRow * lda2 + (kk - Ksplit);
            floatx4 f0 = *(const floatx4*)(Ap);
            floatx4 f1 = *(const floatx4*)(Ap + 4);
            floatx4 f2 = *(const floatx4*)(Ap + 8);
            floatx4 f3 = *(const floatx4*)(Ap + 12);
            union { _Float16 h[16]; uint4 q[2]; } av;
#pragma unroll
            for (int j = 0; j < 4; ++j) {
                av.h[j]      = (_Float16)f0[j];
                av.h[4 + j]  = (_Float16)f1[j];
                av.h[8 + j]  = (_Float16)f2[j];
                av.h[12 + j] = (_Float16)f3[j];
            }
            a0 = av.q[0]; a1 = av.q[1];
        } else {
            const u16* Ap = (const u16*)A1v + (long long)bz * bsA + aRow * lda1 + (k0 + sseg);
            a0 = *(const uint4*)Ap;
            a1 = *(const uint4*)(Ap + 8);
        }
        const u16* Bp = Bsrc + k0;
        const uint4 b0 = *(const uint4*)Bp;
        const uint4 b1 = *(const uint4*)(Bp + 8);

        __syncthreads();                      // prior compute done reading LDS
        *(uint4*)&As[srow][sseg]     = a0;
        *(uint4*)&As[srow][sseg + 8] = a1;
        *(uint4*)&Bs[srow][sseg]     = b0;
        *(uint4*)&Bs[srow][sseg + 8] = b1;
        __syncthreads();

        half8 af[4], bf[4];
#pragma unroll
        for (int i = 0; i < 4; ++i) af[i] = *(const half8*)&As[wm + i*16 + fr][fq*8];
#pragma unroll
        for (int j = 0; j < 4; ++j) bf[j] = *(const half8*)&Bs[wn + j*16 + fr][fq*8];
#pragma unroll
        for (int i = 0; i < 4; ++i)
#pragma unroll
            for (int j = 0; j < 4; ++j)
                acc[i][j] = __builtin_amdgcn_mfma_f32_16x16x32_f16(af[i], bf[j], acc[i][j], 0, 0, 0);
    }

    // D layout (16x16): col = lane&15, row = (lane>>4)*4 + r   [verified m89/m91]
    const int crow0 = tm * 128 + wm + fq * 4;
    const int ccol0 = tn * 128 + wn + fr;
    if (OUT_F16) {
        _Float16* C = (_Float16*)Cv + (long long)bz * bsC;
#pragma unroll
        for (int i = 0; i < 4; ++i)
#pragma unroll
            for (int j = 0; j < 4; ++j) {
                const int col = ccol0 + j * 16;
                const float bv = bias[col];
#pragma unroll
                for (int r = 0; r < 4; ++r)
                    C[(long long)(crow0 + i*16 + r) * ldc + col] = (_Float16)(acc[i][j][r] + bv);
            }
    } else {
        float* C = (float*)Cv + (long long)bz * bsC;
#pragma unroll
        for (int i = 0; i < 4; ++i)
#pragma unroll
            for (int j = 0; j < 4; ++j) {
                const int col = ccol0 + j * 16;
#pragma unroll
                for (int r = 0; r < 4; ++r)
                    C[(long long)(crow0 + i*16 + r) * ldc + col] = acc[i][j][r];
            }
    }
}

// ---------------------------------------------------------------------------
// Length load robust to int32-vs-int64 storage. Lengths are in [1024, 2048),
// so for little-endian int64 the odd 32-bit words are always 0; for int32
// word[1] is a length >= 1024. Unambiguous runtime detection.
// ---------------------------------------------------------------------------
__device__ __forceinline__ int load_len(const int* __restrict__ p, int b)
{
    return (p[1] == 0) ? p[2 * b] : p[b];
}

// ---------------------------------------------------------------------------
// In-place masked softmax over rows of w [Bn][Sq][Sq] (f32).
// Row r of batch b: element c masked iff (r>=lenR[b]) XOR (c>=lenC[b]).
// One 256-thread block per row; 8 elems/thread.
// ---------------------------------------------------------------------------
__global__ __launch_bounds__(256)
void softmax_mask_k(float* __restrict__ w, const int* __restrict__ lenR,
                    const int* __restrict__ lenC)
{
    const int b = blockIdx.y;
    const int r = blockIdx.x;
    float* row = w + ((long long)b * Sq + r) * (long long)Sq;
    const int lr = load_len(lenR, b);
    const int lc = load_len(lenC, b);
    const bool rover = (r >= lr);
    const int tid  = threadIdx.x;
    const int lane = tid & 63;
    const int wave = tid >> 6;

    floatx4 x0 = *(const floatx4*)(row + tid * 8);
    floatx4 x1 = *(const floatx4*)(row + tid * 8 + 4);
    float v[8];
#pragma unroll
    for (int j = 0; j < 4; ++j) { v[j] = x0[j]; v[4 + j] = x1[j]; }

    float m = -3.0e38f;
#pragma unroll
    for (int j = 0; j < 8; ++j) {
        const int c = tid * 8 + j;
        if (rover != (c >= lc)) v[j] = -__builtin_inff();
        m = fmaxf(m, v[j]);
    }
#pragma unroll
    for (int off = 32; off > 0; off >>= 1) m = fmaxf(m, __shfl_xor(m, off, 64));
    __shared__ float redm[4], reds[4];
    if (lane == 0) redm[wave] = m;
    __syncthreads();
    m = fmaxf(fmaxf(redm[0], redm[1]), fmaxf(redm[2], redm[3]));

    float s = 0.f;
#pragma unroll
    for (int j = 0; j < 8; ++j) { v[j] = __expf(v[j] - m); s += v[j]; }
#pragma unroll
    for (int off = 32; off > 0; off >>= 1) s += __shfl_xor(s, off, 64);
    if (lane == 0) reds[wave] = s;
    __syncthreads();
    s = reds[0] + reds[1] + reds[2] + reds[3];
    const float inv = 1.0f / s;   // row never fully masked (lengths in [S/2,S))
#pragma unroll
    for (int j = 0; j < 4; ++j) { x0[j] = v[j] * inv; x1[j] = v[4 + j] * inv; }
    *(floatx4*)(row + tid * 8)     = x0;
    *(floatx4*)(row + tid * 8 + 4) = x1;
}

// ---------------------------------------------------------------------------
extern "C" void kernel_launch(void* const* d_in, const int* in_sizes, int n_in,
                              void* d_out, int out_size, void* d_ws, size_t ws_size,
                              hipStream_t stream)
{
    (void)in_sizes; (void)n_in; (void)out_size; (void)ws_size;
    const float* k1    = (const float*)d_in[0];
    const float* k2    = (const float*)d_in[1];
    const float* pk1in = (const float*)d_in[2];
    const float* pk2in = (const float*)d_in[3];
    const float* v1    = (const float*)d_in[4];
    const float* v2    = (const float*)d_in[5];
    const float* W_k1  = (const float*)d_in[6];
    const float* b_k1  = (const float*)d_in[7];
    const float* W_k2  = (const float*)d_in[8];
    const float* b_k2  = (const float*)d_in[9];
    const float* W_pk1 = (const float*)d_in[10];
    const float* b_pk1 = (const float*)d_in[11];
    const float* W_pk2 = (const float*)d_in[12];
    const float* b_pk2 = (const float*)d_in[13];
    const int* len1 = (const int*)d_in[14];  // k1_lengths (int32 or int64-LE)
    const int* len2 = (const int*)d_in[15];  // k2_lengths

    float* out = (float*)d_out;
    float* o1 = out;                                  // [Bn,Sq,DV]
    float* o2 = o1 + (long long)Bn * Sq * DV;         // [Bn,Sq,DV]
    float* w1 = o2 + (long long)Bn * Sq * DV;         // [Bn,Sq,Sq]
    float* w2 = w1 + (long long)Bn * Sq * Sq;         // [Bn,Sq,Sq]

    // fp16 projections live in the (currently dead) o1/o2 regions; phase 4
    // overwrites those regions last, after the projections are consumed.
    _Float16* k1p = (_Float16*)o1;                    // [Bn*Sq][AD]
    _Float16* k2p = k1p + (long long)Bn * Sq * AD;
    _Float16* pk1 = (_Float16*)o2;
    _Float16* pk2 = pk1 + (long long)Bn * Sq * AD;

    _Float16* vT1   = (_Float16*)d_ws;                // [Bn][DV][Sq]
    _Float16* vT2   = vT1 + (long long)Bn * DV * Sq;
    _Float16* WTk1  = vT2 + (long long)Bn * DV * Sq;  // [AD][KD]
    _Float16* WTk2  = WTk1 + AD * KD;
    _Float16* WTpk1 = WTk2 + AD * KD;                 // [AD][KD+PKD]
    _Float16* WTpk2 = WTpk1 + AD * (KD + PKD);

    // ---- phase 0: transpose-casts (W -> W^T f16, v -> v^T f16) ----
    transpose_cast_k<<<dim3(AD/32, KD/32, 1), 256, 0, stream>>>(W_k1, WTk1, KD, AD, 0, 0);
    transpose_cast_k<<<dim3(AD/32, KD/32, 1), 256, 0, stream>>>(W_k2, WTk2, KD, AD, 0, 0);
    transpose_cast_k<<<dim3(AD/32, (KD+PKD)/32, 1), 256, 0, stream>>>(W_pk1, WTpk1, KD+PKD, AD, 0, 0);
    transpose_cast_k<<<dim3(AD/32, (KD+PKD)/32, 1), 256, 0, stream>>>(W_pk2, WTpk2, KD+PKD, AD, 0, 0);
    transpose_cast_k<<<dim3(DV/32, Sq/32, Bn), 256, 0, stream>>>(v1, vT1, Sq, DV,
        (long long)Sq*DV, (long long)Sq*DV);
    transpose_cast_k<<<dim3(DV/32, Sq/32, Bn), 256, 0, stream>>>(v2, vT2, Sq, DV,
        (long long)Sq*DV, (long long)Sq*DV);

    // ---- phase 1: projections (f32 A on the fly -> f16 out + bias) ----
    const dim3 gProj(AD/128, (Bn*Sq)/128, 1);
    gemm_k<true, true><<<gProj, 256, 0, stream>>>(
        k1, nullptr, KD, KD, 0, 0,  WTk1, KD, 0,  k1p, AD, 0, b_k1, KD);
    gemm_k<true, true><<<gProj, 256, 0, stream>>>(
        k2, nullptr, KD, KD, 0, 0,  WTk2, KD, 0,  k2p, AD, 0, b_k2, KD);
    gemm_k<true, true><<<gProj, 256, 0, stream>>>(
        k1, pk1in, KD, KD, PKD, 0,  WTpk1, KD+PKD, 0,  pk1, AD, 0, b_pk1, KD+PKD);
    gemm_k<true, true><<<gProj, 256, 0, stream>>>(
        k2, pk2in, KD, KD, PKD, 0,  WTpk2, KD+PKD, 0,  pk2, AD, 0, b_pk2, KD+PKD);

    // ---- phase 2: scores, written pre-transposed into w1/w2 regions ----
    // w1_pre[t][s] = sum_a pk2[t][a] * k1p[s][a]  (= score_1^T)
    const dim3 gScore(Sq/128, Sq/128, Bn);
    gemm_k<false, false><<<gScore, 256, 0, stream>>>(
        pk2, nullptr, 0, AD, 0, (long long)Sq*AD,
        k1p, AD, (long long)Sq*AD,
        w1, Sq, (long long)Sq*Sq, nullptr, AD);
    gemm_k<false, false><<<gScore, 256, 0, stream>>>(
        pk1, nullptr, 0, AD, 0, (long long)Sq*AD,
        k2p, AD, (long long)Sq*AD,
        w2, Sq, (long long)Sq*Sq, nullptr, AD);

    // ---- phase 3: masked softmax in place ----
    softmax_mask_k<<<dim3(Sq, Bn), 256, 0, stream>>>(w1, len2, len1);
    softmax_mask_k<<<dim3(Sq, Bn), 256, 0, stream>>>(w2, len1, len2);

    // ---- phase 4: o = w @ v  (w f32 converted on stage, v^T f16) ----
    const dim3 gOut(DV/128, Sq/128, Bn);
    gemm_k<true, false><<<gOut, 256, 0, stream>>>(
        w1, nullptr, Sq, Sq, 0, (long long)Sq*Sq,
        vT1, Sq, (long long)DV*Sq,
        o1, DV, (long long)Sq*DV, nullptr, Sq);
    gemm_k<true, false><<<gOut, 256, 0, stream>>>(
        w2, nullptr, Sq, Sq, 0, (long long)Sq*Sq,
        vT2, Sq, (long long)DV*Sq,
        o2, DV, (long long)Sq*DV, nullptr, Sq);
}

// Round 3
// 935.009 us; speedup vs baseline: 1.0179x; 1.0179x over previous
//
#include <hip/hip_runtime.h>

typedef _Float16 half8 __attribute__((ext_vector_type(8)));
typedef float    floatx4 __attribute__((ext_vector_type(4)));
typedef unsigned short u16;

constexpr int Bn  = 8;
constexpr int Sq  = 2048;   // S1 == S2
constexpr int KD  = 512;    // K1_DIM == K2_DIM
constexpr int PKD = 256;
constexpr int AD  = 512;    // ATT_DIM
constexpr int DV  = 512;

// 16-byte async global->LDS DMA. LDS dest must be wave-uniform base + lane*16.
__device__ __forceinline__ void llds16(const void* g, void* l)
{
    __builtin_amdgcn_global_load_lds(
        (const __attribute__((address_space(1))) unsigned int*)g,
        (__attribute__((address_space(3))) unsigned int*)l, 16, 0, 0);
}

// ---------------------------------------------------------------------------
// transpose + cast f32 -> f16:  out[j][i] = (f16) in[i][j]
// ---------------------------------------------------------------------------
__global__ __launch_bounds__(256)
void transpose_cast_k(const float* __restrict__ in, _Float16* __restrict__ out,
                      int inRows, int inCols, long long bsIn, long long bsOut)
{
    __shared__ float t[32][33];
    const int b = blockIdx.z;
    in  += (long long)b * bsIn;
    out += (long long)b * bsOut;
    const int tx = threadIdx.x & 31;
    const int ty = threadIdx.x >> 5;     // 0..7
    const int c0 = blockIdx.x * 32;
    const int r0 = blockIdx.y * 32;
#pragma unroll
    for (int i = 0; i < 4; ++i)
        t[ty + 8*i][tx] = in[(long long)(r0 + ty + 8*i) * inCols + c0 + tx];
    __syncthreads();
#pragma unroll
    for (int i = 0; i < 4; ++i)
        out[(long long)(c0 + ty + 8*i) * inRows + r0 + tx] = (_Float16)t[tx][ty + 8*i];
}

// ---------------------------------------------------------------------------
// 128x128x32 fp16 MFMA GEMM, m97-style global_load_lds staging.
// C[M][N] = A[M][K] * B^T   (B stored [N][K] f16, k-contiguous)
// A_F32: A is f32 (DMA'd raw, converted on fragment read), with optional
//        two-segment concat source via Ksplit (per-lane segment select).
// LDS tiles are UNPADDED (DMA constraint); bank conflicts broken by XOR
// swizzle of the 16B chunk index with low row bits, applied on the SOURCE
// address at staging time and on the LDS address at fragment-read time.
// ---------------------------------------------------------------------------
template<bool A_F32, bool OUT_F16>
__global__ __launch_bounds__(256, 2)
void gemm_k(const void* __restrict__ A1v, const void* __restrict__ A2v, int Ksplit,
            int lda1, int lda2, long long bsA,
            const _Float16* __restrict__ Bm, int ldb, long long bsB,
            void* __restrict__ Cv, int ldc, long long bsC,
            const float* __restrict__ bias, int K)
{
    __shared__ __align__(16) unsigned char AsRaw[A_F32 ? 16384 : 8192]; // 128x32
    __shared__ __align__(16) unsigned char BsRaw[8192];                 // 128x32 f16

    const int tid  = threadIdx.x;
    const int lane = tid & 63;
    const int wave = tid >> 6;
    const int wm   = (wave >> 1) * 64;
    const int wn   = (wave & 1) * 64;
    const int fr   = lane & 15;       // frag row (A) / col (B,D)
    const int fq   = lane >> 4;       // quad: k-offset fq*8, D-row fq*4

    const int tm = blockIdx.y, tn = blockIdx.x, bz = blockIdx.z;
    const long long aRowBase = (long long)tm * 128;
    const long long bRowBase = (long long)tn * 128;
    const _Float16* Bbase = Bm + (long long)bz * bsB;

    floatx4 acc[4][4];
#pragma unroll
    for (int i = 0; i < 4; ++i)
#pragma unroll
        for (int j = 0; j < 4; ++j) acc[i][j] = (floatx4)0.0f;

    for (int k0 = 0; k0 < K; k0 += 32) {
        __syncthreads();   // previous tile's ds_reads complete before overwrite

        if (A_F32) {
            const float* A1 = (const float*)A1v + (long long)bz * bsA;
            const float* A2 = (const float*)A2v;
#pragma unroll
            for (int is = 0; is < 4; ++is) {
                const int r  = (tid >> 3) + is * 32;       // 0..127
                const int ch = (tid & 7) ^ (r & 7);        // swizzled 16B chunk
                const int kk = k0 + ch * 4;                // f32 col
                const float* src = (kk < Ksplit)
                    ? A1 + (aRowBase + r) * lda1 + kk
                    : A2 + (aRowBase + r) * lda2 + (kk - Ksplit);
                llds16(src, AsRaw + tid * 16 + is * 4096);
            }
        } else {
            const _Float16* A1 = (const _Float16*)A1v + (long long)bz * bsA;
#pragma unroll
            for (int is = 0; is < 2; ++is) {
                const int r  = (tid >> 2) + is * 64;       // 0..127
                const int ch = (tid & 3) ^ (r & 3);
                llds16(A1 + (aRowBase + r) * lda1 + k0 + ch * 8,
                       AsRaw + tid * 16 + is * 4096);
            }
        }
#pragma unroll
        for (int is = 0; is < 2; ++is) {
            const int r  = (tid >> 2) + is * 64;
            const int ch = (tid & 3) ^ (r & 3);
            llds16(Bbase + (bRowBase + r) * ldb + k0 + ch * 8,
                   BsRaw + tid * 16 + is * 4096);
        }

        __syncthreads();   // drains vmcnt(0): DMA visible to all waves

        half8 af[4], bf[4];
        if (A_F32) {
            const float* As32 = (const float*)AsRaw;
#pragma unroll
            for (int i = 0; i < 4; ++i) {
                const int r  = wm + i * 16 + fr;
                const int c0 = ((2 * fq) ^ (r & 7)) * 4;
                const int c1 = ((2 * fq + 1) ^ (r & 7)) * 4;
                floatx4 f0 = *(const floatx4*)(As32 + r * 32 + c0);
                floatx4 f1 = *(const floatx4*)(As32 + r * 32 + c1);
                half8 h;
#pragma unroll
                for (int j = 0; j < 4; ++j) {
                    h[j]     = (_Float16)f0[j];
                    h[4 + j] = (_Float16)f1[j];
                }
                af[i] = h;
            }
        } else {
            const _Float16* As16 = (const _Float16*)AsRaw;
#pragma unroll
            for (int i = 0; i < 4; ++i) {
                const int r  = wm + i * 16 + fr;
                const int ch = fq ^ (r & 3);
                af[i] = *(const half8*)(As16 + r * 32 + ch * 8);
            }
        }
        {
            const _Float16* Bs16 = (const _Float16*)BsRaw;
#pragma unroll
            for (int j = 0; j < 4; ++j) {
                const int r  = wn + j * 16 + fr;
                const int ch = fq ^ (r & 3);
                bf[j] = *(const half8*)(Bs16 + r * 32 + ch * 8);
            }
        }
#pragma unroll
        for (int i = 0; i < 4; ++i)
#pragma unroll
            for (int j = 0; j < 4; ++j)
                acc[i][j] = __builtin_amdgcn_mfma_f32_16x16x32_f16(af[i], bf[j], acc[i][j], 0, 0, 0);
    }

    // D layout (16x16): col = lane&15, row = (lane>>4)*4 + r   [verified m89/m91]
    const int crow0 = tm * 128 + wm + fq * 4;
    const int ccol0 = tn * 128 + wn + fr;
    if (OUT_F16) {
        _Float16* C = (_Float16*)Cv + (long long)bz * bsC;
#pragma unroll
        for (int i = 0; i < 4; ++i)
#pragma unroll
            for (int j = 0; j < 4; ++j) {
                const int col = ccol0 + j * 16;
                const float bv = bias[col];
#pragma unroll
                for (int r = 0; r < 4; ++r)
                    C[(long long)(crow0 + i*16 + r) * ldc + col] = (_Float16)(acc[i][j][r] + bv);
            }
    } else {
        float* C = (float*)Cv + (long long)bz * bsC;
#pragma unroll
        for (int i = 0; i < 4; ++i)
#pragma unroll
            for (int j = 0; j < 4; ++j) {
                const int col = ccol0 + j * 16;
#pragma unroll
                for (int r = 0; r < 4; ++r)
                    C[(long long)(crow0 + i*16 + r) * ldc + col] = acc[i][j][r];
            }
    }
}

// ---------------------------------------------------------------------------
// Length load robust to int32-vs-int64 storage (lengths in [1024,2048) so an
// int64-LE buffer has word[1]==0, an int32 buffer has word[1]>=1024).
// ---------------------------------------------------------------------------
__device__ __forceinline__ int load_len(const int* __restrict__ p, int b)
{
    return (p[1] == 0) ? p[2 * b] : p[b];
}

// ---------------------------------------------------------------------------
// In-place masked softmax over rows of w [Bn][Sq][Sq] (f32), optional f16
// copy for the downstream o-GEMM. Mask: (r>=lenR[b]) XOR (c>=lenC[b]).
// ---------------------------------------------------------------------------
__global__ __launch_bounds__(256)
void softmax_mask_k(float* __restrict__ w, _Float16* __restrict__ wh,
                    const int* __restrict__ lenR, const int* __restrict__ lenC)
{
    const int b = blockIdx.y;
    const int r = blockIdx.x;
    const long long rowOff = ((long long)b * Sq + r) * (long long)Sq;
    float* row = w + rowOff;
    const int lr = load_len(lenR, b);
    const int lc = load_len(lenC, b);
    const bool rover = (r >= lr);
    const int tid  = threadIdx.x;
    const int lane = tid & 63;
    const int wave = tid >> 6;

    floatx4 x0 = *(const floatx4*)(row + tid * 8);
    floatx4 x1 = *(const floatx4*)(row + tid * 8 + 4);
    float v[8];
#pragma unroll
    for (int j = 0; j < 4; ++j) { v[j] = x0[j]; v[4 + j] = x1[j]; }

    float m = -3.0e38f;
#pragma unroll
    for (int j = 0; j < 8; ++j) {
        const int c = tid * 8 + j;
        if (rover != (c >= lc)) v[j] = -__builtin_inff();
        m = fmaxf(m, v[j]);
    }
#pragma unroll
    for (int off = 32; off > 0; off >>= 1) m = fmaxf(m, __shfl_xor(m, off, 64));
    __shared__ float redm[4], reds[4];
    if (lane == 0) redm[wave] = m;
    __syncthreads();
    m = fmaxf(fmaxf(redm[0], redm[1]), fmaxf(redm[2], redm[3]));

    float s = 0.f;
#pragma unroll
    for (int j = 0; j < 8; ++j) { v[j] = __expf(v[j] - m); s += v[j]; }
#pragma unroll
    for (int off = 32; off > 0; off >>= 1) s += __shfl_xor(s, off, 64);
    if (lane == 0) reds[wave] = s;
    __syncthreads();
    s = reds[0] + reds[1] + reds[2] + reds[3];
    const float inv = 1.0f / s;   // row never fully masked (lengths in [S/2,S))
#pragma unroll
    for (int j = 0; j < 4; ++j) { x0[j] = v[j] * inv; x1[j] = v[4 + j] * inv; }
    *(floatx4*)(row + tid * 8)     = x0;
    *(floatx4*)(row + tid * 8 + 4) = x1;
    if (wh != nullptr) {
        half8 h;
#pragma unroll
        for (int j = 0; j < 4; ++j) { h[j] = (_Float16)x0[j]; h[4 + j] = (_Float16)x1[j]; }
        *(half8*)(wh + rowOff + tid * 8) = h;
    }
}

// ---------------------------------------------------------------------------
extern "C" void kernel_launch(void* const* d_in, const int* in_sizes, int n_in,
                              void* d_out, int out_size, void* d_ws, size_t ws_size,
                              hipStream_t stream)
{
    (void)in_sizes; (void)n_in; (void)out_size;
    const float* k1    = (const float*)d_in[0];
    const float* k2    = (const float*)d_in[1];
    const float* pk1in = (const float*)d_in[2];
    const float* pk2in = (const float*)d_in[3];
    const float* v1    = (const float*)d_in[4];
    const float* v2    = (const float*)d_in[5];
    const float* W_k1  = (const float*)d_in[6];
    const float* b_k1  = (const float*)d_in[7];
    const float* W_k2  = (const float*)d_in[8];
    const float* b_k2  = (const float*)d_in[9];
    const float* W_pk1 = (const float*)d_in[10];
    const float* b_pk1 = (const float*)d_in[11];
    const float* W_pk2 = (const float*)d_in[12];
    const float* b_pk2 = (const float*)d_in[13];
    const int* len1 = (const int*)d_in[14];
    const int* len2 = (const int*)d_in[15];

    float* out = (float*)d_out;
    float* o1 = out;                                  // [Bn,Sq,DV]
    float* o2 = o1 + (long long)Bn * Sq * DV;         // [Bn,Sq,DV]
    float* w1 = o2 + (long long)Bn * Sq * DV;         // [Bn,Sq,Sq]
    float* w2 = w1 + (long long)Bn * Sq * Sq;         // [Bn,Sq,Sq]

    // fp16 projections live in the (dead until phase 4) o1/o2 regions.
    _Float16* k1p = (_Float16*)o1;                    // [Bn*Sq][AD]
    _Float16* k2p = k1p + (long long)Bn * Sq * AD;
    _Float16* pk1 = (_Float16*)o2;
    _Float16* pk2 = pk1 + (long long)Bn * Sq * AD;

    _Float16* vT1   = (_Float16*)d_ws;                // [Bn][DV][Sq]
    _Float16* vT2   = vT1 + (long long)Bn * DV * Sq;
    _Float16* WTk1  = vT2 + (long long)Bn * DV * Sq;  // [AD][KD]
    _Float16* WTk2  = WTk1 + AD * KD;
    _Float16* WTpk1 = WTk2 + AD * KD;                 // [AD][KD+PKD]
    _Float16* WTpk2 = WTpk1 + AD * (KD + PKD);

    const unsigned long long fixedHalves =
        2ull * Bn * DV * Sq + 2ull * AD * KD + 2ull * AD * (KD + PKD);
    _Float16* w1h = (_Float16*)d_ws + fixedHalves;    // [Bn][Sq][Sq] f16
    _Float16* w2h = w1h + (long long)Bn * Sq * Sq;
    const bool fast =
        ws_size >= (fixedHalves + 2ull * Bn * Sq * Sq) * sizeof(_Float16);

    // ---- phase 0: transpose-casts ----
    transpose_cast_k<<<dim3(AD/32, KD/32, 1), 256, 0, stream>>>(W_k1, WTk1, KD, AD, 0, 0);
    transpose_cast_k<<<dim3(AD/32, KD/32, 1), 256, 0, stream>>>(W_k2, WTk2, KD, AD, 0, 0);
    transpose_cast_k<<<dim3(AD/32, (KD+PKD)/32, 1), 256, 0, stream>>>(W_pk1, WTpk1, KD+PKD, AD, 0, 0);
    transpose_cast_k<<<dim3(AD/32, (KD+PKD)/32, 1), 256, 0, stream>>>(W_pk2, WTpk2, KD+PKD, AD, 0, 0);
    transpose_cast_k<<<dim3(DV/32, Sq/32, Bn), 256, 0, stream>>>(v1, vT1, Sq, DV,
        (long long)Sq*DV, (long long)Sq*DV);
    transpose_cast_k<<<dim3(DV/32, Sq/32, Bn), 256, 0, stream>>>(v2, vT2, Sq, DV,
        (long long)Sq*DV, (long long)Sq*DV);

    // ---- phase 1: projections (f32 A DMA'd + converted, f16 out + bias) ----
    const dim3 gProj(AD/128, (Bn*Sq)/128, 1);
    gemm_k<true, true><<<gProj, 256, 0, stream>>>(
        k1, k1, KD, KD, KD, 0,  WTk1, KD, 0,  k1p, AD, 0, b_k1, KD);
    gemm_k<true, true><<<gProj, 256, 0, stream>>>(
        k2, k2, KD, KD, KD, 0,  WTk2, KD, 0,  k2p, AD, 0, b_k2, KD);
    gemm_k<true, true><<<gProj, 256, 0, stream>>>(
        k1, pk1in, KD, KD, PKD, 0,  WTpk1, KD+PKD, 0,  pk1, AD, 0, b_pk1, KD+PKD);
    gemm_k<true, true><<<gProj, 256, 0, stream>>>(
        k2, pk2in, KD, KD, PKD, 0,  WTpk2, KD+PKD, 0,  pk2, AD, 0, b_pk2, KD+PKD);

    // ---- phase 2: scores (pure f16 fast path), pre-transposed into w1/w2 ----
    const dim3 gScore(Sq/128, Sq/128, Bn);
    gemm_k<false, false><<<gScore, 256, 0, stream>>>(
        pk2, pk2, 0, AD, AD, (long long)Sq*AD,
        k1p, AD, (long long)Sq*AD,
        w1, Sq, (long long)Sq*Sq, nullptr, AD);
    gemm_k<false, false><<<gScore, 256, 0, stream>>>(
        pk1, pk1, 0, AD, AD, (long long)Sq*AD,
        k2p, AD, (long long)Sq*AD,
        w2, Sq, (long long)Sq*Sq, nullptr, AD);

    // ---- phase 3: masked softmax in place (+f16 copy when ws allows) ----
    softmax_mask_k<<<dim3(Sq, Bn), 256, 0, stream>>>(w1, fast ? w1h : nullptr, len2, len1);
    softmax_mask_k<<<dim3(Sq, Bn), 256, 0, stream>>>(w2, fast ? w2h : nullptr, len1, len2);

    // ---- phase 4: o = w @ v ----
    const dim3 gOut(DV/128, Sq/128, Bn);
    if (fast) {
        gemm_k<false, false><<<gOut, 256, 0, stream>>>(
            w1h, w1h, 0, Sq, Sq, (long long)Sq*Sq,
            vT1, Sq, (long long)DV*Sq,
            o1, DV, (long long)Sq*DV, nullptr, Sq);
        gemm_k<false, false><<<gOut, 256, 0, stream>>>(
            w2h, w2h, 0, Sq, Sq, (long long)Sq*Sq,
            vT2, Sq, (long long)DV*Sq,
            o2, DV, (long long)Sq*DV, nullptr, Sq);
    } else {
        gemm_k<true, false><<<gOut, 256, 0, stream>>>(
            w1, w1, Sq, Sq, Sq, (long long)Sq*Sq,
            vT1, Sq, (long long)DV*Sq,
            o1, DV, (long long)Sq*DV, nullptr, Sq);
        gemm_k<true, false><<<gOut, 256, 0, stream>>>(
            w2, w2, Sq, Sq, Sq, (long long)Sq*Sq,
            vT2, Sq, (long long)DV*Sq,
            o2, DV, (long long)Sq*DV, nullptr, Sq);
    }
}